// Round 1
// baseline (686.248 us; speedup 1.0000x reference)
//
#include <hip/hip_runtime.h>
#include <math.h>

#define TSEQ 4096
#define NQH 16
#define NKVH 8
#define HD 128
#define WINSZ 1024
#define QT 128      // q rows per block (4 waves x 2 stripes x 16)
#define KT 64       // kv rows per tile

#define KSTR 136    // sK row stride in halves (128 + 8 pad, 16B-aligned rows)
#define VSTR 72     // sV row stride in halves (64 + 8 pad)
#define PSTR 72     // sP row stride in halves

typedef _Float16 h8 __attribute__((ext_vector_type(8)));
typedef _Float16 h4 __attribute__((ext_vector_type(4)));
typedef float    f4 __attribute__((ext_vector_type(4)));

// Flash sliding-window attention, GQA 16q/8kv, d=128, window=1024 (inclusive of self).
// MFMA 16x16x32 f16. C/D layout: col=lane&15, row=(lane>>4)*4+reg (m89/m91).
// A layout: A[m=lane&15][k=quad*8+j+32*ks]. B layout: B[k=quad*8+j+32*ks][n=lane&15].
__global__ __launch_bounds__(256, 2)
void fa_swa_kernel(const float* __restrict__ Qg, const float* __restrict__ Kg,
                   const float* __restrict__ Vg, float* __restrict__ Og) {
  __shared__ _Float16 sK[KT * KSTR];          // [s][dd] fp16
  __shared__ _Float16 sV[HD * VSTR];          // [dd][s] fp16 (transposed)
  __shared__ _Float16 sP[4][2][16 * PSTR];    // per-wave, per-stripe P buffer

  const int tid  = threadIdx.x;
  const int w    = tid >> 6;
  const int lane = tid & 63;
  const int quad = lane >> 4;
  const int ln   = lane & 15;

  const int qt = blockIdx.x;
  const int h  = blockIdx.y;
  const int bz = blockIdx.z;
  const int hk = h >> 1;
  const int q0 = qt * QT;

  // ---- Q fragments in registers (A-layout), fp32 -> fp16 ----
  h8 qf[2][4];
  #pragma unroll
  for (int r = 0; r < 2; ++r) {
    const int qg = q0 + w * 32 + r * 16 + ln;
    const float* qp = Qg + ((size_t)((size_t)bz * TSEQ + qg) * NQH + h) * HD + quad * 8;
    #pragma unroll
    for (int ks = 0; ks < 4; ++ks) {
      f4 a = *(const f4*)(qp + ks * 32);
      f4 b = *(const f4*)(qp + ks * 32 + 4);
      h8 qv;
      qv[0] = (_Float16)a[0]; qv[1] = (_Float16)a[1];
      qv[2] = (_Float16)a[2]; qv[3] = (_Float16)a[3];
      qv[4] = (_Float16)b[0]; qv[5] = (_Float16)b[1];
      qv[6] = (_Float16)b[2]; qv[7] = (_Float16)b[3];
      qf[r][ks] = qv;
    }
  }

  f4 Oacc[2][8];
  #pragma unroll
  for (int r = 0; r < 2; ++r)
    #pragma unroll
    for (int c = 0; c < 8; ++c)
      Oacc[r][c] = (f4){0.f, 0.f, 0.f, 0.f};

  float mrow[2][4], lrow[2][4];
  #pragma unroll
  for (int r = 0; r < 2; ++r)
    #pragma unroll
    for (int g = 0; g < 4; ++g) { mrow[r][g] = -INFINITY; lrow[r][g] = 0.f; }

  int s_begin = q0 - WINSZ; if (s_begin < 0) s_begin = 0;   // multiple of 64
  const int s_end = q0 + QT;

  const float* kbase = Kg + ((size_t)((size_t)bz * TSEQ) * NKVH + hk) * HD;
  const float* vbase = Vg + ((size_t)((size_t)bz * TSEQ) * NKVH + hk) * HD;

  for (int s0 = s_begin; s0 < s_end; s0 += KT) {
    __syncthreads();   // protect sK/sV from previous iteration's readers

    // ---- stage K tile: sK[s][dd], block-linear coalesced loads ----
    {
      const float* kp = kbase + (size_t)s0 * (NKVH * HD);
      #pragma unroll
      for (int i = 0; i < 8; ++i) {
        int e   = tid + 256 * i;     // float4 index within 64x128 tile
        int row = e >> 5;
        int c4  = (e & 31) * 4;
        f4 x = *(const f4*)(kp + (size_t)row * (NKVH * HD) + c4);
        h4 hv;
        hv[0] = (_Float16)x[0]; hv[1] = (_Float16)x[1];
        hv[2] = (_Float16)x[2]; hv[3] = (_Float16)x[3];
        *(h4*)(&sK[row * KSTR + c4]) = hv;
      }
    }
    // ---- stage V tile transposed: sV[dd][s]; lane->s mapping keeps writes 2-way max ----
    {
      const int srow = tid & 63;
      const int dd0  = (tid >> 6) * 32;
      const float* vp = vbase + (size_t)(s0 + srow) * (NKVH * HD) + dd0;
      #pragma unroll
      for (int f = 0; f < 8; ++f) {
        f4 x = *(const f4*)(vp + f * 4);
        #pragma unroll
        for (int c = 0; c < 4; ++c)
          sV[(dd0 + f * 4 + c) * VSTR + srow] = (_Float16)x[c];
      }
    }
    __syncthreads();

    // ---- per-wave compute: 2 stripes of 16 q-rows ----
    #pragma unroll
    for (int r = 0; r < 2; ++r) {
      // S = Q K^T  (16 x 64)
      f4 S[4];
      #pragma unroll
      for (int ct = 0; ct < 4; ++ct) {
        f4 acc = (f4){0.f, 0.f, 0.f, 0.f};
        #pragma unroll
        for (int ks = 0; ks < 4; ++ks) {
          h8 kb = *(const h8*)(&sK[(ct * 16 + ln) * KSTR + quad * 8 + ks * 32]);
          acc = __builtin_amdgcn_mfma_f32_16x16x32_f16(qf[r][ks], kb, acc, 0, 0, 0);
        }
        S[ct] = acc;
      }

      // mask + online softmax (state replicated across each quad's 16 lanes)
      const int qrb = q0 + w * 32 + r * 16 + quad * 4;
      float mnew[4], psum[4];
      #pragma unroll
      for (int g = 0; g < 4; ++g) {
        const int q = qrb + g;
        float mx = -INFINITY;
        #pragma unroll
        for (int ct = 0; ct < 4; ++ct) {
          const int s = s0 + ct * 16 + ln;
          const int d = q - s;
          const bool ok = (d >= 0) && (d < WINSZ);
          float v = ok ? S[ct][g] : -INFINITY;
          S[ct][g] = v;
          mx = fmaxf(mx, v);
        }
        #pragma unroll
        for (int off = 1; off < 16; off <<= 1)
          mx = fmaxf(mx, __shfl_xor(mx, off, 64));
        float mn = fmaxf(mrow[r][g], mx);
        mnew[g] = mn;
        float sum = 0.f;
        #pragma unroll
        for (int ct = 0; ct < 4; ++ct) {
          float v = S[ct][g];
          float p = (v == -INFINITY) ? 0.f : __expf(v - mn);
          S[ct][g] = p;
          sum += p;
        }
        #pragma unroll
        for (int off = 1; off < 16; off <<= 1)
          sum += __shfl_xor(sum, off, 64);
        psum[g] = sum;
      }

      #pragma unroll
      for (int g = 0; g < 4; ++g) {
        const float mn = mnew[g];
        const float alpha = (mn == -INFINITY) ? 1.f : __expf(mrow[r][g] - mn);
        mrow[r][g] = mn;
        lrow[r][g] = lrow[r][g] * alpha + psum[g];
        #pragma unroll
        for (int ct = 0; ct < 8; ++ct)
          Oacc[r][ct][g] *= alpha;
      }

      // P (C-layout) -> LDS -> A-layout
      #pragma unroll
      for (int ct = 0; ct < 4; ++ct)
        #pragma unroll
        for (int g = 0; g < 4; ++g)
          sP[w][r][(quad * 4 + g) * PSTR + ct * 16 + ln] = (_Float16)S[ct][g];

      __asm__ volatile("s_waitcnt lgkmcnt(0)" ::: "memory");  // wave-private RAW

      // O += P V   (16 x 128)
      #pragma unroll
      for (int ks = 0; ks < 2; ++ks) {
        h8 pa = *(const h8*)(&sP[w][r][ln * PSTR + quad * 8 + ks * 32]);
        #pragma unroll
        for (int ct = 0; ct < 8; ++ct) {
          h8 vb = *(const h8*)(&sV[(ct * 16 + ln) * VSTR + quad * 8 + ks * 32]);
          Oacc[r][ct] = __builtin_amdgcn_mfma_f32_16x16x32_f16(pa, vb, Oacc[r][ct], 0, 0, 0);
        }
      }
    }
  }

  // ---- epilogue: O / l, fp32 stores ----
  #pragma unroll
  for (int r = 0; r < 2; ++r) {
    const int qrb = q0 + w * 32 + r * 16 + quad * 4;
    float inv[4];
    #pragma unroll
    for (int g = 0; g < 4; ++g) inv[g] = 1.f / lrow[r][g];
    #pragma unroll
    for (int ct = 0; ct < 8; ++ct)
      #pragma unroll
      for (int g = 0; g < 4; ++g)
        Og[((size_t)((size_t)bz * TSEQ + (qrb + g)) * NQH + h) * HD + ct * 16 + ln] =
            Oacc[r][ct][g] * inv[g];
  }
}

extern "C" void kernel_launch(void* const* d_in, const int* in_sizes, int n_in,
                              void* d_out, int out_size, void* d_ws, size_t ws_size,
                              hipStream_t stream) {
  const float* Q = (const float*)d_in[0];
  const float* K = (const float*)d_in[1];
  const float* V = (const float*)d_in[2];
  float* O = (float*)d_out;
  const int batch = in_sizes[0] / (TSEQ * NQH * HD);   // 4
  dim3 grid(TSEQ / QT, NQH, batch);
  fa_swa_kernel<<<grid, 256, 0, stream>>>(Q, K, V, O);
}